// Round 9
// baseline (51.199 us; speedup 1.0000x reference)
//
#include <hip/hip_runtime.h>
#include <hip/hip_bf16.h>

// Forward warp (bilinear splatting), per-tile gather, 4 tiles per block with
// 1-ahead register prefetch (round-trip latency hidden under LDS atomics).
//   img  [B=8, C=3, H=180, W=320] f32
//   flow [B=8, 2,  H=180, W=320] f32
//   scale=4 -> out [B, C, 720, 1280] f32
//
// Tile 40x64, margin 6: window 24x30=720 input px per tile (3 items/thread).
// Pixels with |flow| > 6 are excluded by the EXACT complement predicate and
// splatted by a vectorized global-atomic kernel (exact for ANY input).
// All 15 loads per tile per thread are issued unconditionally and batched
// (single counted-vmcnt wait); tile t+1's loads issue before tile t's first
// use. Write-out is fused with acc re-zero. Exclusive nontemporal float4
// stores -> no output memset, no workspace.

typedef float f32x4 __attribute__((ext_vector_type(4)));

#define B_ 8
#define C_ 3
#define H_ 180
#define W_ 320
#define HW_ (H_ * W_)
#define SCALE_ 4
#define Ho_ (H_ * SCALE_)            // 720
#define Wo_ (W_ * SCALE_)            // 1280
#define TH_ 40
#define TW_ 64
#define NTY_ (Ho_ / TH_)             // 18
#define NTX_ (Wo_ / TW_)             // 20
#define NTILES_ (B_ * NTY_ * NTX_)   // 2880
#define NPIX_ (B_ * H_ * W_)         // 460800

#define TPB_ 4                       // tiles per block (adjacent in x)
#define NBLK_ (NTILES_ / TPB_)       // 720 (divisible by 8 -> bijective XCD swizzle)
#define KXG_ (NTX_ / TPB_)           // 5 tile-groups per row

#define MARGIN_ 6.0f
#define MARGIN_I_ 6
#define WIN_H_ (TH_ / 4 + 2 * MARGIN_I_ + 2)   // 24
#define WIN_W_ (TW_ / 4 + 2 * MARGIN_I_ + 2)   // 30
#define WIN_ITEMS_ (WIN_H_ * WIN_W_)           // 720 (3 items/thread @256)
#define ITEMS_PT_ 3
#define PLANE_STRIDE_ 2564                     // 2560+4: channel atomics -> distinct banks
#define LDS_FLOATS_ (C_ * PLANE_STRIDE_)       // 7692 floats = 30768 B

__global__ __launch_bounds__(256, 4) void warp_tile_kernel(const float* __restrict__ img,
                                                           const float* __restrict__ flow,
                                                           float* __restrict__ out) {
    __shared__ __align__(16) float acc[LDS_FLOATS_];
    const int tid = threadIdx.x;

    // XCD-chunked swizzle over 720 blocks (720 % 8 == 0 -> bijective).
    int blk = (int)(blockIdx.x & 7) * (NBLK_ / 8) + (int)(blockIdx.x >> 3);
    const int kx = blk % KXG_;
    const int t2 = blk / KXG_;
    const int ty = t2 % NTY_;
    const int b  = t2 / NTY_;
    const int py0 = ty * TH_;
    const int hb  = py0 >> 2;

    const float* __restrict__ fxp  = flow + (size_t)(b * 2 + 0) * HW_;
    const float* __restrict__ fyp  = flow + (size_t)(b * 2 + 1) * HW_;
    const float* __restrict__ imgb = img + (size_t)b * C_ * HW_;
    const size_t outb = (size_t)b * C_ * Ho_ * Wo_;
    const size_t chs  = (size_t)Ho_ * Wo_;

    // double-buffered per-tile register payloads
    float fxv[2][ITEMS_PT_], fyv[2][ITEMS_PT_];
    float v0v[2][ITEMS_PT_], v1v[2][ITEMS_PT_], v2v[2][ITEMS_PT_];

    // ---- issue all 15 loads for tile t into buffer s (unconditional, batched) ----
    auto issue = [&](int t, int s) {
        const int wb = ((kx * TPB_ + t) * TW_) >> 2;
        #pragma unroll
        for (int k = 0; k < ITEMS_PT_; ++k) {
            int i = tid + k * 256;
            int r = i / WIN_W_;
            int c = i - r * WIN_W_;
            int h = hb - (MARGIN_I_ + 1) + r;
            int w = wb - (MARGIN_I_ + 1) + c;
            bool act = (i < WIN_ITEMS_) &&
                       ((unsigned)h < (unsigned)H_) && ((unsigned)w < (unsigned)W_);
            int hw = act ? (h * W_ + w) : 0;
            fxv[s][k] = fxp[hw];
            fyv[s][k] = fyp[hw];
            v0v[s][k] = imgb[hw];
            v1v[s][k] = imgb[HW_ + hw];
            v2v[s][k] = imgb[2 * HW_ + hw];
        }
    };

    // ---- consume buffer s for tile t: predicate + hit test + LDS atomics ----
    auto accumulate = [&](int t, int s) {
        const int px0 = (kx * TPB_ + t) * TW_;
        const int wb = px0 >> 2;
        #pragma unroll
        for (int k = 0; k < ITEMS_PT_; ++k) {
            int i = tid + k * 256;
            int r = i / WIN_W_;
            int c = i - r * WIN_W_;
            int h = hb - (MARGIN_I_ + 1) + r;
            int w = wb - (MARGIN_I_ + 1) + c;
            bool act = (i < WIN_ITEMS_) &&
                       ((unsigned)h < (unsigned)H_) && ((unsigned)w < (unsigned)W_);
            float fx = fxv[s][k], fy = fyv[s][k];
            // Must be the EXACT complement of outlier_kernel's predicate.
            if (!(act && fabsf(fx) <= MARGIN_ && fabsf(fy) <= MARGIN_)) continue;

            float x = ((float)w + fx) * (float)SCALE_;
            float y = ((float)h + fy) * (float)SCALE_;
            float x0f = floorf(x), y0f = floorf(y);
            int ix0 = (int)x0f - px0;   // tile-local
            int iy0 = (int)y0f - py0;
            bool cx0 = (unsigned)ix0 < (unsigned)TW_;
            bool cx1 = (unsigned)(ix0 + 1) < (unsigned)TW_;
            bool cy0 = (unsigned)iy0 < (unsigned)TH_;
            bool cy1 = (unsigned)(iy0 + 1) < (unsigned)TH_;
            if (!((cx0 | cx1) & (cy0 | cy1))) continue;

            float ax = x - x0f, ay = y - y0f;
            float wxs[2] = {1.0f - ax, ax};
            float wys[2] = {1.0f - ay, ay};
            bool cxs[2] = {cx0, cx1};
            bool cys[2] = {cy0, cy1};
            #pragma unroll
            for (int ky = 0; ky < 2; ++ky) {
                if (!cys[ky]) continue;
                #pragma unroll
                for (int kxx = 0; kxx < 2; ++kxx) {
                    if (!cxs[kxx]) continue;
                    float wt = wxs[kxx] * wys[ky];
                    int la = (iy0 + ky) * TW_ + (ix0 + kxx);
                    atomicAdd(&acc[la], v0v[s][k] * wt);
                    atomicAdd(&acc[la + PLANE_STRIDE_], v1v[s][k] * wt);
                    atomicAdd(&acc[la + 2 * PLANE_STRIDE_], v2v[s][k] * wt);
                }
            }
        }
    };

    // ---- nontemporal write-out fused with acc re-zero ----
    auto writeout_zero = [&](int t) {
        const int px0 = (kx * TPB_ + t) * TW_;
        const int F4_TOTAL = C_ * TH_ * TW_ / 4;   // 1920
        const int F4_PER_PLANE = TH_ * TW_ / 4;    // 640
        const int F4_PER_ROW = TW_ / 4;            // 16
        for (int j = tid; j < F4_TOTAL; j += 256) {
            int ch  = j / F4_PER_PLANE;
            int rem = j - ch * F4_PER_PLANE;
            int yy  = rem / F4_PER_ROW;
            int xx4 = rem - yy * F4_PER_ROW;
            float* lp = &acc[ch * PLANE_STRIDE_ + yy * TW_ + xx4 * 4];
            f32x4 v = *reinterpret_cast<const f32x4*>(lp);
            __builtin_nontemporal_store(v,
                reinterpret_cast<f32x4*>(
                    &out[outb + (size_t)ch * chs + (size_t)(py0 + yy) * Wo_ + px0 + xx4 * 4]));
            *reinterpret_cast<f32x4*>(lp) = (f32x4)(0.f);
        }
    };

    // ---- pipelined 4-tile loop ----
    issue(0, 0);
    for (int j = tid; j < LDS_FLOATS_ / 4; j += 256)
        *reinterpret_cast<f32x4*>(&acc[j * 4]) = (f32x4)(0.f);
    __syncthreads();

    #pragma unroll
    for (int t = 0; t < TPB_; ++t) {
        if (t < TPB_ - 1) issue(t + 1, (t + 1) & 1);   // prefetch before first use of t
        accumulate(t, t & 1);
        __syncthreads();
        writeout_zero(t);
        __syncthreads();
    }
}

// Pixels with |flow| > MARGIN_: exact global-atomic splat (AFTER tile writes).
// Vectorized: 4 px/thread via f32x4 flow loads; fast path = all inliers.
__global__ __launch_bounds__(256) void outlier_kernel(const float* __restrict__ img,
                                                      const float* __restrict__ flow,
                                                      float* __restrict__ out) {
    int q = blockIdx.x * 256 + threadIdx.x;   // grid exactly NPIX_/4/256 = 450
    int idx = q * 4;
    int b = idx / HW_;                         // HW_ % 4 == 0 -> same b for all 4
    int hw = idx - b * HW_;
    f32x4 fx4 = *reinterpret_cast<const f32x4*>(&flow[(size_t)(b * 2 + 0) * HW_ + hw]);
    f32x4 fy4 = *reinterpret_cast<const f32x4*>(&flow[(size_t)(b * 2 + 1) * HW_ + hw]);

    bool ol[4];
    bool any = false;
    #pragma unroll
    for (int j = 0; j < 4; ++j) {
        ol[j] = !(fabsf(fx4[j]) <= MARGIN_ && fabsf(fy4[j]) <= MARGIN_);
        any |= ol[j];
    }
    if (!any) return;

    const float* imgb = img + (size_t)b * C_ * HW_;
    const size_t out_b = (size_t)b * C_ * Ho_ * Wo_;
    const size_t chs = (size_t)Ho_ * Wo_;
    #pragma unroll
    for (int j = 0; j < 4; ++j) {
        if (!ol[j]) continue;
        int hwj = hw + j;
        int h = hwj / W_;
        int w = hwj - h * W_;
        float x = ((float)w + fx4[j]) * (float)SCALE_;
        float y = ((float)h + fy4[j]) * (float)SCALE_;
        float x0f = floorf(x), y0f = floorf(y);
        float ax = x - x0f, ay = y - y0f;
        int ix0 = (int)x0f, iy0 = (int)y0f;
        float v0 = imgb[hwj];
        float v1 = imgb[HW_ + hwj];
        float v2 = imgb[2 * HW_ + hwj];
        float wxs[2] = {1.0f - ax, ax};
        float wys[2] = {1.0f - ay, ay};
        #pragma unroll
        for (int ky = 0; ky < 2; ++ky) {
            int yi = iy0 + ky;
            if ((unsigned)yi >= (unsigned)Ho_) continue;
            #pragma unroll
            for (int kx = 0; kx < 2; ++kx) {
                int xi = ix0 + kx;
                if ((unsigned)xi >= (unsigned)Wo_) continue;
                float wt = wxs[kx] * wys[ky];
                size_t base = out_b + (size_t)yi * Wo_ + (size_t)xi;
                atomicAdd(&out[base + 0 * chs], v0 * wt);
                atomicAdd(&out[base + 1 * chs], v1 * wt);
                atomicAdd(&out[base + 2 * chs], v2 * wt);
            }
        }
    }
}

// ---------------- fallback: naive global-atomic splat (scale != 4) ----------------
__global__ __launch_bounds__(256) void splat_naive(const float* __restrict__ img,
                                                   const float* __restrict__ flow,
                                                   const int* __restrict__ scale_p,
                                                   float* __restrict__ out) {
    int idx = blockIdx.x * blockDim.x + threadIdx.x;
    if (idx >= NPIX_) return;
    const int s = *scale_p;
    const int Ho = H_ * s, Wo = W_ * s;
    int w = idx % W_;
    int t = idx / W_;
    int h = t % H_;
    int b = t / H_;
    const int hw = h * W_ + w;
    float fx = flow[((b * 2 + 0) * H_) * W_ + hw];
    float fy = flow[((b * 2 + 1) * H_) * W_ + hw];
    float x = ((float)w + fx) * (float)s;
    float y = ((float)h + fy) * (float)s;
    float x0f = floorf(x), y0f = floorf(y);
    float ax = x - x0f, ay = y - y0f;
    int ix0 = (int)x0f, iy0 = (int)y0f;
    const size_t img_b = (size_t)b * C_ * HW_;
    float v0 = img[img_b + 0 * (size_t)HW_ + hw];
    float v1 = img[img_b + 1 * (size_t)HW_ + hw];
    float v2 = img[img_b + 2 * (size_t)HW_ + hw];
    const size_t out_b = (size_t)b * C_ * Ho * Wo;
    const size_t out_chs = (size_t)Ho * Wo;
    float wxs[2] = {1.0f - ax, ax};
    float wys[2] = {1.0f - ay, ay};
    #pragma unroll
    for (int ky = 0; ky < 2; ++ky) {
        int yi = iy0 + ky;
        if (yi < 0 || yi > Ho - 1) continue;
        #pragma unroll
        for (int kx = 0; kx < 2; ++kx) {
            int xi = ix0 + kx;
            if (xi < 0 || xi > Wo - 1) continue;
            float wt = wxs[kx] * wys[ky];
            size_t base = out_b + (size_t)yi * Wo + (size_t)xi;
            atomicAdd(&out[base + 0 * out_chs], v0 * wt);
            atomicAdd(&out[base + 1 * out_chs], v1 * wt);
            atomicAdd(&out[base + 2 * out_chs], v2 * wt);
        }
    }
}

extern "C" void kernel_launch(void* const* d_in, const int* in_sizes, int n_in,
                              void* d_out, int out_size, void* d_ws, size_t ws_size,
                              hipStream_t stream) {
    const float* img   = (const float*)d_in[0];
    const float* flow  = (const float*)d_in[1];
    const int*   scale = (const int*)d_in[2];
    float* out = (float*)d_out;

    const bool scale4 = (out_size == B_ * C_ * Ho_ * Wo_);

    if (scale4) {
        warp_tile_kernel<<<NBLK_, 256, 0, stream>>>(img, flow, out);
        outlier_kernel<<<NPIX_ / 4 / 256, 256, 0, stream>>>(img, flow, out);
    } else {
        (void)hipMemsetAsync(out, 0, (size_t)out_size * sizeof(float), stream);
        splat_naive<<<(NPIX_ + 255) / 256, 256, 0, stream>>>(img, flow, scale, out);
    }
}

// Round 10
// 49.516 us; speedup vs baseline: 1.0340x; 1.0340x over previous
//
#include <hip/hip_runtime.h>
#include <hip/hip_bf16.h>

// Forward warp (bilinear splatting), direct per-tile gather-from-window.
//   img  [B=8, C=3, H=180, W=320] f32
//   flow [B=8, 2,  H=180, W=320] f32
//   scale=4 -> out [B, C, 720, 1280] f32
//
// R10: R7 skeleton (one tile/block, ALL window loads unconditional+batched,
// single vmcnt wait) with 512 threads/block for 24 waves/CU, margin 6
// (window 24x30=720 items, <=2/thread), even-aligned window x-start.
// Pixels with |flow| > 6 go through the EXACT-complement outlier kernel.
// Exclusive nontemporal float4 write-out -> no memset, no workspace.

typedef float f32x4 __attribute__((ext_vector_type(4)));

#define B_ 8
#define C_ 3
#define H_ 180
#define W_ 320
#define HW_ (H_ * W_)
#define SCALE_ 4
#define Ho_ (H_ * SCALE_)            // 720
#define Wo_ (W_ * SCALE_)            // 1280
#define TH_ 40
#define TW_ 64
#define NTY_ (Ho_ / TH_)             // 18
#define NTX_ (Wo_ / TW_)             // 20
#define NTILES_ (B_ * NTY_ * NTX_)   // 2880 (divisible by 8 -> bijective XCD swizzle)
#define NPIX_ (B_ * H_ * W_)         // 460800

#define NT_ 512                      // threads per block (8 waves)
#define MARGIN_ 6.0f
#define MARGIN_I_ 6
#define WIN_H_ 24                    // rows hb-7 .. hb+16  (TH/4 + 2*6 + 2)
#define WIN_W_ 30                    // cols wb-8 .. wb+21  (even start for coalescing)
#define WIN_ITEMS_ (WIN_H_ * WIN_W_) // 720 (<= 2*512)
#define ITEMS_PT_ 2
#define PLANE_STRIDE_ 2564           // 2560+4: channel atomics -> distinct banks, 16B-aligned
#define LDS_FLOATS_ (C_ * PLANE_STRIDE_)   // 7692 floats = 30768 B -> LDS allows 5 blk/CU

__global__ __launch_bounds__(NT_, 6) void warp_tile_kernel(const float* __restrict__ img,
                                                           const float* __restrict__ flow,
                                                           float* __restrict__ out) {
    __shared__ __align__(16) float acc[LDS_FLOATS_];
    const int tid = threadIdx.x;

    // XCD-chunked swizzle (2880 % 8 == 0 -> bijective).
    int tile = (int)(blockIdx.x & 7) * (NTILES_ / 8) + (int)(blockIdx.x >> 3);
    const int tx = tile % NTX_;
    const int tt = tile / NTX_;
    const int ty = tt % NTY_;
    const int b  = tt / NTY_;
    const int px0 = tx * TW_;
    const int py0 = ty * TH_;

    for (int j = tid; j < LDS_FLOATS_ / 4; j += NT_)
        *reinterpret_cast<f32x4*>(&acc[j * 4]) = (f32x4)(0.f);

    const float* __restrict__ fxp  = flow + (size_t)(b * 2 + 0) * HW_;
    const float* __restrict__ fyp  = flow + (size_t)(b * 2 + 1) * HW_;
    const float* __restrict__ imgb = img + (size_t)b * C_ * HW_;

    const int hb = py0 >> 2;
    const int wb = px0 >> 2;

    // ---- phase 1: ALL loads unconditional, batched (single counted wait) ----
    float fxv[ITEMS_PT_], fyv[ITEMS_PT_];
    float v0v[ITEMS_PT_], v1v[ITEMS_PT_], v2v[ITEMS_PT_];
    #pragma unroll
    for (int k = 0; k < ITEMS_PT_; ++k) {
        int i = tid + k * NT_;
        int r = i / WIN_W_;
        int c = i - r * WIN_W_;
        int h = hb - 7 + r;
        int w = wb - 8 + c;
        bool act = (i < WIN_ITEMS_) &&
                   ((unsigned)h < (unsigned)H_) && ((unsigned)w < (unsigned)W_);
        int hw = act ? (h * W_ + w) : 0;
        fxv[k] = fxp[hw];
        fyv[k] = fyp[hw];
        v0v[k] = imgb[hw];
        v1v[k] = imgb[HW_ + hw];
        v2v[k] = imgb[2 * HW_ + hw];
    }
    __syncthreads();   // acc zeroed (placed after load issue; loads not LDS-dependent)

    // ---- phase 2: predicate + geometry + LDS atomics ----
    #pragma unroll
    for (int k = 0; k < ITEMS_PT_; ++k) {
        int i = tid + k * NT_;
        int r = i / WIN_W_;
        int c = i - r * WIN_W_;
        int h = hb - 7 + r;
        int w = wb - 8 + c;
        bool act = (i < WIN_ITEMS_) &&
                   ((unsigned)h < (unsigned)H_) && ((unsigned)w < (unsigned)W_);
        float fx = fxv[k], fy = fyv[k];
        // Must be the EXACT complement of outlier_kernel's predicate.
        if (!(act && fabsf(fx) <= MARGIN_ && fabsf(fy) <= MARGIN_)) continue;

        float x = ((float)w + fx) * (float)SCALE_;
        float y = ((float)h + fy) * (float)SCALE_;
        float x0f = floorf(x), y0f = floorf(y);
        int ix0 = (int)x0f - px0;   // tile-local
        int iy0 = (int)y0f - py0;
        bool cx0 = (unsigned)ix0 < (unsigned)TW_;
        bool cx1 = (unsigned)(ix0 + 1) < (unsigned)TW_;
        bool cy0 = (unsigned)iy0 < (unsigned)TH_;
        bool cy1 = (unsigned)(iy0 + 1) < (unsigned)TH_;
        if (!((cx0 | cx1) & (cy0 | cy1))) continue;

        float ax = x - x0f, ay = y - y0f;
        float wxs[2] = {1.0f - ax, ax};
        float wys[2] = {1.0f - ay, ay};
        bool cxs[2] = {cx0, cx1};
        bool cys[2] = {cy0, cy1};
        #pragma unroll
        for (int ky = 0; ky < 2; ++ky) {
            if (!cys[ky]) continue;
            #pragma unroll
            for (int kx = 0; kx < 2; ++kx) {
                if (!cxs[kx]) continue;
                float wt = wxs[kx] * wys[ky];
                int la = (iy0 + ky) * TW_ + (ix0 + kx);
                atomicAdd(&acc[la], v0v[k] * wt);
                atomicAdd(&acc[la + PLANE_STRIDE_], v1v[k] * wt);
                atomicAdd(&acc[la + 2 * PLANE_STRIDE_], v2v[k] * wt);
            }
        }
    }
    __syncthreads();

    // ---- phase 3: exclusive coalesced nontemporal float4 write-out ----
    const size_t outb = (size_t)b * C_ * Ho_ * Wo_;
    const size_t chs  = (size_t)Ho_ * Wo_;
    const int F4_PER_PLANE = TH_ * TW_ / 4;        // 640
    const int F4_PER_ROW   = TW_ / 4;              // 16
    for (int j = tid; j < C_ * F4_PER_PLANE; j += NT_) {
        int ch  = j / F4_PER_PLANE;
        int rem = j - ch * F4_PER_PLANE;
        int yy  = rem / F4_PER_ROW;
        int xx4 = rem - yy * F4_PER_ROW;
        f32x4 v = *reinterpret_cast<const f32x4*>(&acc[ch * PLANE_STRIDE_ + yy * TW_ + xx4 * 4]);
        __builtin_nontemporal_store(v,
            reinterpret_cast<f32x4*>(
                &out[outb + (size_t)ch * chs + (size_t)(py0 + yy) * Wo_ + px0 + xx4 * 4]));
    }
}

// Pixels with |flow| > MARGIN_: exact global-atomic splat (AFTER tile writes).
// Vectorized: 4 px/thread via f32x4 flow loads; fast path = all inliers.
__global__ __launch_bounds__(256) void outlier_kernel(const float* __restrict__ img,
                                                      const float* __restrict__ flow,
                                                      float* __restrict__ out) {
    int q = blockIdx.x * 256 + threadIdx.x;   // grid exactly NPIX_/4/256 = 450
    int idx = q * 4;
    int b = idx / HW_;                         // HW_ % 4 == 0 -> same b for all 4
    int hw = idx - b * HW_;
    f32x4 fx4 = *reinterpret_cast<const f32x4*>(&flow[(size_t)(b * 2 + 0) * HW_ + hw]);
    f32x4 fy4 = *reinterpret_cast<const f32x4*>(&flow[(size_t)(b * 2 + 1) * HW_ + hw]);

    bool ol[4];
    bool any = false;
    #pragma unroll
    for (int j = 0; j < 4; ++j) {
        ol[j] = !(fabsf(fx4[j]) <= MARGIN_ && fabsf(fy4[j]) <= MARGIN_);
        any |= ol[j];
    }
    if (!any) return;

    const float* imgb = img + (size_t)b * C_ * HW_;
    const size_t out_b = (size_t)b * C_ * Ho_ * Wo_;
    const size_t chs = (size_t)Ho_ * Wo_;
    #pragma unroll
    for (int j = 0; j < 4; ++j) {
        if (!ol[j]) continue;
        int hwj = hw + j;
        int h = hwj / W_;
        int w = hwj - h * W_;
        float x = ((float)w + fx4[j]) * (float)SCALE_;
        float y = ((float)h + fy4[j]) * (float)SCALE_;
        float x0f = floorf(x), y0f = floorf(y);
        float ax = x - x0f, ay = y - y0f;
        int ix0 = (int)x0f, iy0 = (int)y0f;
        float v0 = imgb[hwj];
        float v1 = imgb[HW_ + hwj];
        float v2 = imgb[2 * HW_ + hwj];
        float wxs[2] = {1.0f - ax, ax};
        float wys[2] = {1.0f - ay, ay};
        #pragma unroll
        for (int ky = 0; ky < 2; ++ky) {
            int yi = iy0 + ky;
            if ((unsigned)yi >= (unsigned)Ho_) continue;
            #pragma unroll
            for (int kx = 0; kx < 2; ++kx) {
                int xi = ix0 + kx;
                if ((unsigned)xi >= (unsigned)Wo_) continue;
                float wt = wxs[kx] * wys[ky];
                size_t base = out_b + (size_t)yi * Wo_ + (size_t)xi;
                atomicAdd(&out[base + 0 * chs], v0 * wt);
                atomicAdd(&out[base + 1 * chs], v1 * wt);
                atomicAdd(&out[base + 2 * chs], v2 * wt);
            }
        }
    }
}

// ---------------- fallback: naive global-atomic splat (scale != 4) ----------------
__global__ __launch_bounds__(256) void splat_naive(const float* __restrict__ img,
                                                   const float* __restrict__ flow,
                                                   const int* __restrict__ scale_p,
                                                   float* __restrict__ out) {
    int idx = blockIdx.x * blockDim.x + threadIdx.x;
    if (idx >= NPIX_) return;
    const int s = *scale_p;
    const int Ho = H_ * s, Wo = W_ * s;
    int w = idx % W_;
    int t = idx / W_;
    int h = t % H_;
    int b = t / H_;
    const int hw = h * W_ + w;
    float fx = flow[((b * 2 + 0) * H_) * W_ + hw];
    float fy = flow[((b * 2 + 1) * H_) * W_ + hw];
    float x = ((float)w + fx) * (float)s;
    float y = ((float)h + fy) * (float)s;
    float x0f = floorf(x), y0f = floorf(y);
    float ax = x - x0f, ay = y - y0f;
    int ix0 = (int)x0f, iy0 = (int)y0f;
    const size_t img_b = (size_t)b * C_ * HW_;
    float v0 = img[img_b + 0 * (size_t)HW_ + hw];
    float v1 = img[img_b + 1 * (size_t)HW_ + hw];
    float v2 = img[img_b + 2 * (size_t)HW_ + hw];
    const size_t out_b = (size_t)b * C_ * Ho * Wo;
    const size_t out_chs = (size_t)Ho * Wo;
    float wxs[2] = {1.0f - ax, ax};
    float wys[2] = {1.0f - ay, ay};
    #pragma unroll
    for (int ky = 0; ky < 2; ++ky) {
        int yi = iy0 + ky;
        if (yi < 0 || yi > Ho - 1) continue;
        #pragma unroll
        for (int kx = 0; kx < 2; ++kx) {
            int xi = ix0 + kx;
            if (xi < 0 || xi > Wo - 1) continue;
            float wt = wxs[kx] * wys[ky];
            size_t base = out_b + (size_t)yi * Wo + (size_t)xi;
            atomicAdd(&out[base + 0 * out_chs], v0 * wt);
            atomicAdd(&out[base + 1 * out_chs], v1 * wt);
            atomicAdd(&out[base + 2 * out_chs], v2 * wt);
        }
    }
}

extern "C" void kernel_launch(void* const* d_in, const int* in_sizes, int n_in,
                              void* d_out, int out_size, void* d_ws, size_t ws_size,
                              hipStream_t stream) {
    const float* img   = (const float*)d_in[0];
    const float* flow  = (const float*)d_in[1];
    const int*   scale = (const int*)d_in[2];
    float* out = (float*)d_out;

    const bool scale4 = (out_size == B_ * C_ * Ho_ * Wo_);

    if (scale4) {
        warp_tile_kernel<<<NTILES_, NT_, 0, stream>>>(img, flow, out);
        outlier_kernel<<<NPIX_ / 4 / 256, 256, 0, stream>>>(img, flow, out);
    } else {
        (void)hipMemsetAsync(out, 0, (size_t)out_size * sizeof(float), stream);
        splat_naive<<<(NPIX_ + 255) / 256, 256, 0, stream>>>(img, flow, scale, out);
    }
}

// Round 11
// 48.026 us; speedup vs baseline: 1.0661x; 1.0310x over previous
//
#include <hip/hip_runtime.h>
#include <hip/hip_bf16.h>

// Forward warp (bilinear splatting), direct per-tile gather-from-window.
//   img  [B=8, C=3, H=180, W=320] f32
//   flow [B=8, 2,  H=180, W=320] f32
//   scale=4 -> out [B, C, 720, 1280] f32
//
// R11 = R7 champion skeleton (one 40x64 tile per 256-thread block, ALL window
// loads unconditional + batched into one counted wait) with margin 6
// (window 24x30=720 items, 3/thread, 15 loads/thread) and load-issue hoisted
// above the LDS-zero loop so zeroing hides load latency.
// Pixels with |flow| > 6 are handled by the EXACT-complement vectorized
// outlier kernel (global atomics AFTER tile stores; exact for ANY input).
// Exclusive nontemporal float4 write-out -> no memset, no workspace.

typedef float f32x4 __attribute__((ext_vector_type(4)));

#define B_ 8
#define C_ 3
#define H_ 180
#define W_ 320
#define HW_ (H_ * W_)
#define SCALE_ 4
#define Ho_ (H_ * SCALE_)            // 720
#define Wo_ (W_ * SCALE_)            // 1280
#define TH_ 40
#define TW_ 64
#define NTY_ (Ho_ / TH_)             // 18
#define NTX_ (Wo_ / TW_)             // 20
#define NTILES_ (B_ * NTY_ * NTX_)   // 2880 (divisible by 8 -> bijective XCD swizzle)
#define NPIX_ (B_ * H_ * W_)         // 460800

#define NT_ 256
#define MARGIN_ 6.0f
#define WIN_H_ 24                    // rows hb-7 .. hb+16  (TH/4 + 2*6 + 2)
#define WIN_W_ 30                    // cols wb-8 .. wb+21  (even start for coalescing)
#define WIN_ITEMS_ (WIN_H_ * WIN_W_) // 720 (<= 3*256)
#define ITEMS_PT_ 3
#define PLANE_STRIDE_ 2564           // 2560+4: channel atomics -> distinct banks, 16B-aligned
#define LDS_FLOATS_ (C_ * PLANE_STRIDE_)   // 7692 floats = 30768 B -> 5 blocks/CU

__global__ __launch_bounds__(NT_) void warp_tile_kernel(const float* __restrict__ img,
                                                        const float* __restrict__ flow,
                                                        float* __restrict__ out) {
    __shared__ __align__(16) float acc[LDS_FLOATS_];
    const int tid = threadIdx.x;

    // XCD-chunked swizzle (2880 % 8 == 0 -> bijective); each XCD ends up
    // owning one batch image -> per-XCD L2 working set ~1.2 MB (resident).
    int tile = (int)(blockIdx.x & 7) * (NTILES_ / 8) + (int)(blockIdx.x >> 3);
    const int tx = tile % NTX_;
    const int tt = tile / NTX_;
    const int ty = tt % NTY_;
    const int b  = tt / NTY_;
    const int px0 = tx * TW_;
    const int py0 = ty * TH_;

    const float* __restrict__ fxp  = flow + (size_t)(b * 2 + 0) * HW_;
    const float* __restrict__ fyp  = flow + (size_t)(b * 2 + 1) * HW_;
    const float* __restrict__ imgb = img + (size_t)b * C_ * HW_;

    const int hb = py0 >> 2;
    const int wb = px0 >> 2;

    // ---- phase 1: ALL loads unconditional, batched (issued BEFORE LDS zero) ----
    float fxv[ITEMS_PT_], fyv[ITEMS_PT_];
    float v0v[ITEMS_PT_], v1v[ITEMS_PT_], v2v[ITEMS_PT_];
    bool av[ITEMS_PT_];
    #pragma unroll
    for (int k = 0; k < ITEMS_PT_; ++k) {
        int i = tid + k * NT_;
        int r = i / WIN_W_;
        int c = i - r * WIN_W_;
        int h = hb - 7 + r;
        int w = wb - 8 + c;
        bool act = (i < WIN_ITEMS_) &&
                   ((unsigned)h < (unsigned)H_) && ((unsigned)w < (unsigned)W_);
        av[k] = act;
        int hw = act ? (h * W_ + w) : 0;
        fxv[k] = fxp[hw];
        fyv[k] = fyp[hw];
        v0v[k] = imgb[hw];
        v1v[k] = imgb[HW_ + hw];
        v2v[k] = imgb[2 * HW_ + hw];
    }

    // LDS zero overlaps the in-flight loads (no dependence).
    for (int j = tid; j < LDS_FLOATS_ / 4; j += NT_)
        *reinterpret_cast<f32x4*>(&acc[j * 4]) = (f32x4)(0.f);
    __syncthreads();

    // ---- phase 2: predicate + geometry + LDS atomics ----
    #pragma unroll
    for (int k = 0; k < ITEMS_PT_; ++k) {
        int i = tid + k * NT_;
        int r = i / WIN_W_;
        int c = i - r * WIN_W_;
        int h = hb - 7 + r;
        int w = wb - 8 + c;
        float fx = fxv[k], fy = fyv[k];
        // Must be the EXACT complement of outlier_kernel's predicate.
        if (!(av[k] && fabsf(fx) <= MARGIN_ && fabsf(fy) <= MARGIN_)) continue;

        float x = ((float)w + fx) * (float)SCALE_;
        float y = ((float)h + fy) * (float)SCALE_;
        float x0f = floorf(x), y0f = floorf(y);
        int ix0 = (int)x0f - px0;   // tile-local
        int iy0 = (int)y0f - py0;
        bool cx0 = (unsigned)ix0 < (unsigned)TW_;
        bool cx1 = (unsigned)(ix0 + 1) < (unsigned)TW_;
        bool cy0 = (unsigned)iy0 < (unsigned)TH_;
        bool cy1 = (unsigned)(iy0 + 1) < (unsigned)TH_;
        if (!((cx0 | cx1) & (cy0 | cy1))) continue;

        float ax = x - x0f, ay = y - y0f;
        float wxs[2] = {1.0f - ax, ax};
        float wys[2] = {1.0f - ay, ay};
        bool cxs[2] = {cx0, cx1};
        bool cys[2] = {cy0, cy1};
        #pragma unroll
        for (int ky = 0; ky < 2; ++ky) {
            if (!cys[ky]) continue;
            #pragma unroll
            for (int kx = 0; kx < 2; ++kx) {
                if (!cxs[kx]) continue;
                float wt = wxs[kx] * wys[ky];
                int la = (iy0 + ky) * TW_ + (ix0 + kx);
                atomicAdd(&acc[la], v0v[k] * wt);
                atomicAdd(&acc[la + PLANE_STRIDE_], v1v[k] * wt);
                atomicAdd(&acc[la + 2 * PLANE_STRIDE_], v2v[k] * wt);
            }
        }
    }
    __syncthreads();

    // ---- phase 3: exclusive coalesced nontemporal float4 write-out ----
    const size_t outb = (size_t)b * C_ * Ho_ * Wo_;
    const size_t chs  = (size_t)Ho_ * Wo_;
    const int F4_PER_PLANE = TH_ * TW_ / 4;        // 640
    const int F4_PER_ROW   = TW_ / 4;              // 16
    for (int j = tid; j < C_ * F4_PER_PLANE; j += NT_) {
        int ch  = j / F4_PER_PLANE;
        int rem = j - ch * F4_PER_PLANE;
        int yy  = rem / F4_PER_ROW;
        int xx4 = rem - yy * F4_PER_ROW;
        f32x4 v = *reinterpret_cast<const f32x4*>(&acc[ch * PLANE_STRIDE_ + yy * TW_ + xx4 * 4]);
        __builtin_nontemporal_store(v,
            reinterpret_cast<f32x4*>(
                &out[outb + (size_t)ch * chs + (size_t)(py0 + yy) * Wo_ + px0 + xx4 * 4]));
    }
}

// Pixels with |flow| > MARGIN_: exact global-atomic splat (AFTER tile writes).
// Vectorized: 4 px/thread via f32x4 flow loads; fast path = all inliers.
__global__ __launch_bounds__(256) void outlier_kernel(const float* __restrict__ img,
                                                      const float* __restrict__ flow,
                                                      float* __restrict__ out) {
    int q = blockIdx.x * 256 + threadIdx.x;   // grid exactly NPIX_/4/256 = 450
    int idx = q * 4;
    int b = idx / HW_;                         // HW_ % 4 == 0 -> same b for all 4
    int hw = idx - b * HW_;
    f32x4 fx4 = *reinterpret_cast<const f32x4*>(&flow[(size_t)(b * 2 + 0) * HW_ + hw]);
    f32x4 fy4 = *reinterpret_cast<const f32x4*>(&flow[(size_t)(b * 2 + 1) * HW_ + hw]);

    bool ol[4];
    bool any = false;
    #pragma unroll
    for (int j = 0; j < 4; ++j) {
        ol[j] = !(fabsf(fx4[j]) <= MARGIN_ && fabsf(fy4[j]) <= MARGIN_);
        any |= ol[j];
    }
    if (!any) return;

    const float* imgb = img + (size_t)b * C_ * HW_;
    const size_t out_b = (size_t)b * C_ * Ho_ * Wo_;
    const size_t chs = (size_t)Ho_ * Wo_;
    #pragma unroll
    for (int j = 0; j < 4; ++j) {
        if (!ol[j]) continue;
        int hwj = hw + j;
        int h = hwj / W_;
        int w = hwj - h * W_;
        float x = ((float)w + fx4[j]) * (float)SCALE_;
        float y = ((float)h + fy4[j]) * (float)SCALE_;
        float x0f = floorf(x), y0f = floorf(y);
        float ax = x - x0f, ay = y - y0f;
        int ix0 = (int)x0f, iy0 = (int)y0f;
        float v0 = imgb[hwj];
        float v1 = imgb[HW_ + hwj];
        float v2 = imgb[2 * HW_ + hwj];
        float wxs[2] = {1.0f - ax, ax};
        float wys[2] = {1.0f - ay, ay};
        #pragma unroll
        for (int ky = 0; ky < 2; ++ky) {
            int yi = iy0 + ky;
            if ((unsigned)yi >= (unsigned)Ho_) continue;
            #pragma unroll
            for (int kx = 0; kx < 2; ++kx) {
                int xi = ix0 + kx;
                if ((unsigned)xi >= (unsigned)Wo_) continue;
                float wt = wxs[kx] * wys[ky];
                size_t base = out_b + (size_t)yi * Wo_ + (size_t)xi;
                atomicAdd(&out[base + 0 * chs], v0 * wt);
                atomicAdd(&out[base + 1 * chs], v1 * wt);
                atomicAdd(&out[base + 2 * chs], v2 * wt);
            }
        }
    }
}

// ---------------- fallback: naive global-atomic splat (scale != 4) ----------------
__global__ __launch_bounds__(256) void splat_naive(const float* __restrict__ img,
                                                   const float* __restrict__ flow,
                                                   const int* __restrict__ scale_p,
                                                   float* __restrict__ out) {
    int idx = blockIdx.x * blockDim.x + threadIdx.x;
    if (idx >= NPIX_) return;
    const int s = *scale_p;
    const int Ho = H_ * s, Wo = W_ * s;
    int w = idx % W_;
    int t = idx / W_;
    int h = t % H_;
    int b = t / H_;
    const int hw = h * W_ + w;
    float fx = flow[((b * 2 + 0) * H_) * W_ + hw];
    float fy = flow[((b * 2 + 1) * H_) * W_ + hw];
    float x = ((float)w + fx) * (float)s;
    float y = ((float)h + fy) * (float)s;
    float x0f = floorf(x), y0f = floorf(y);
    float ax = x - x0f, ay = y - y0f;
    int ix0 = (int)x0f, iy0 = (int)y0f;
    const size_t img_b = (size_t)b * C_ * HW_;
    float v0 = img[img_b + 0 * (size_t)HW_ + hw];
    float v1 = img[img_b + 1 * (size_t)HW_ + hw];
    float v2 = img[img_b + 2 * (size_t)HW_ + hw];
    const size_t out_b = (size_t)b * C_ * Ho * Wo;
    const size_t out_chs = (size_t)Ho * Wo;
    float wxs[2] = {1.0f - ax, ax};
    float wys[2] = {1.0f - ay, ay};
    #pragma unroll
    for (int ky = 0; ky < 2; ++ky) {
        int yi = iy0 + ky;
        if (yi < 0 || yi > Ho - 1) continue;
        #pragma unroll
        for (int kx = 0; kx < 2; ++kx) {
            int xi = ix0 + kx;
            if (xi < 0 || xi > Wo - 1) continue;
            float wt = wxs[kx] * wys[ky];
            size_t base = out_b + (size_t)yi * Wo + (size_t)xi;
            atomicAdd(&out[base + 0 * out_chs], v0 * wt);
            atomicAdd(&out[base + 1 * out_chs], v1 * wt);
            atomicAdd(&out[base + 2 * out_chs], v2 * wt);
        }
    }
}

extern "C" void kernel_launch(void* const* d_in, const int* in_sizes, int n_in,
                              void* d_out, int out_size, void* d_ws, size_t ws_size,
                              hipStream_t stream) {
    const float* img   = (const float*)d_in[0];
    const float* flow  = (const float*)d_in[1];
    const int*   scale = (const int*)d_in[2];
    float* out = (float*)d_out;

    const bool scale4 = (out_size == B_ * C_ * Ho_ * Wo_);

    if (scale4) {
        warp_tile_kernel<<<NTILES_, NT_, 0, stream>>>(img, flow, out);
        outlier_kernel<<<NPIX_ / 4 / 256, 256, 0, stream>>>(img, flow, out);
    } else {
        (void)hipMemsetAsync(out, 0, (size_t)out_size * sizeof(float), stream);
        splat_naive<<<(NPIX_ + 255) / 256, 256, 0, stream>>>(img, flow, scale, out);
    }
}

// Round 12
// 44.878 us; speedup vs baseline: 1.1408x; 1.0701x over previous
//
#include <hip/hip_runtime.h>
#include <hip/hip_bf16.h>

// Forward warp (bilinear splatting), direct per-tile gather-from-window.
//   img  [B=8, C=3, H=180, W=320] f32
//   flow [B=8, 2,  H=180, W=320] f32
//   scale=4 -> out [B, C, 720, 1280] f32
//
// R12 = R7 champion tile kernel VERBATIM (best measured: 43.7 us):
//   one 40x64 tile per 256-thread block; margin 8 (window 28x34=952, 4
//   items/thread); phase order zero -> sync -> batched unconditional loads
//   -> atomics -> sync -> writeout; plane stride 2564; XCD swizzle;
//   nontemporal f32x4 exclusive write-out (no memset, no workspace).
// Only change vs R7: vectorized outlier kernel (4 px/thread f32x4 flow read,
// 450 blocks, fast all-inlier exit), EXACT complement predicate at margin 8.

typedef float f32x4 __attribute__((ext_vector_type(4)));

#define B_ 8
#define C_ 3
#define H_ 180
#define W_ 320
#define HW_ (H_ * W_)
#define SCALE_ 4
#define Ho_ (H_ * SCALE_)            // 720
#define Wo_ (W_ * SCALE_)            // 1280
#define TH_ 40
#define TW_ 64
#define NTY_ (Ho_ / TH_)             // 18
#define NTX_ (Wo_ / TW_)             // 20
#define NTILES_ (B_ * NTY_ * NTX_)   // 2880 (divisible by 8 -> bijective XCD swizzle)
#define NPIX_ (B_ * H_ * W_)         // 460800

#define MARGIN_ 8.0f
#define MARGIN_I_ 8
#define WIN_H_ (TH_ / 4 + 2 * MARGIN_I_ + 2)   // 28
#define WIN_W_ (TW_ / 4 + 2 * MARGIN_I_ + 2)   // 34
#define WIN_ITEMS_ (WIN_H_ * WIN_W_)           // 952  (<= 4*256)
#define PLANE_STRIDE_ 2564                     // 2560+4: channels -> distinct banks, 16B-aligned
#define LDS_FLOATS_ (C_ * PLANE_STRIDE_)       // 7692 floats = 30768 B -> 5 blocks/CU

__global__ __launch_bounds__(256) void warp_tile_kernel(const float* __restrict__ img,
                                                        const float* __restrict__ flow,
                                                        float* __restrict__ out) {
    __shared__ __align__(16) float acc[LDS_FLOATS_];

    // XCD-chunked swizzle: consecutive hardware blockIdx round-robin across the
    // 8 XCDs; remap so each XCD owns a contiguous (spatially local) tile range.
    int tile = (int)(blockIdx.x & 7) * (NTILES_ / 8) + (int)(blockIdx.x >> 3);
    const int tx = tile % NTX_;
    const int tt = tile / NTX_;
    const int ty = tt % NTY_;
    const int b  = tt / NTY_;
    const int px0 = tx * TW_;
    const int py0 = ty * TH_;

    for (int j = threadIdx.x; j < LDS_FLOATS_ / 4; j += 256)
        *reinterpret_cast<f32x4*>(&acc[j * 4]) = (f32x4)(0.f);
    __syncthreads();

    const float* __restrict__ fxp  = flow + (size_t)(b * 2 + 0) * HW_;
    const float* __restrict__ fyp  = flow + (size_t)(b * 2 + 1) * HW_;
    const float* __restrict__ imgb = img + (size_t)b * C_ * HW_;

    const int hb = py0 >> 2;
    const int wb = px0 >> 2;

    // ---- phase 1: batched independent loads (break dependent-latency chains) ----
    float fxv[4], fyv[4], v0v[4], v1v[4], v2v[4];
    int hv[4], wv[4];
    bool av[4];
    #pragma unroll
    for (int k = 0; k < 4; ++k) {
        int i = (int)threadIdx.x + k * 256;
        int r = i / WIN_W_;
        int c = i - r * WIN_W_;
        int h = hb - (MARGIN_I_ + 1) + r;
        int w = wb - (MARGIN_I_ + 1) + c;
        bool act = (i < WIN_ITEMS_) &&
                   ((unsigned)h < (unsigned)H_) && ((unsigned)w < (unsigned)W_);
        int hw = act ? (h * W_ + w) : 0;
        av[k] = act; hv[k] = h; wv[k] = w;
        fxv[k] = fxp[hw];
        fyv[k] = fyp[hw];
        v0v[k] = imgb[hw];
        v1v[k] = imgb[HW_ + hw];
        v2v[k] = imgb[2 * HW_ + hw];
    }

    // ---- phase 2: predicate + hit-test + LDS accumulate ----
    #pragma unroll
    for (int k = 0; k < 4; ++k) {
        if (!av[k]) continue;
        float fx = fxv[k], fy = fyv[k];
        // Must be the EXACT complement of outlier_kernel's predicate.
        if (!(fabsf(fx) <= MARGIN_ && fabsf(fy) <= MARGIN_)) continue;

        float x = ((float)wv[k] + fx) * (float)SCALE_;
        float y = ((float)hv[k] + fy) * (float)SCALE_;
        float x0f = floorf(x), y0f = floorf(y);
        int ix0 = (int)x0f - px0;   // tile-local
        int iy0 = (int)y0f - py0;
        bool cx0 = (unsigned)ix0 < (unsigned)TW_;
        bool cx1 = (unsigned)(ix0 + 1) < (unsigned)TW_;
        bool cy0 = (unsigned)iy0 < (unsigned)TH_;
        bool cy1 = (unsigned)(iy0 + 1) < (unsigned)TH_;
        if (!((cx0 | cx1) & (cy0 | cy1))) continue;

        float ax = x - x0f, ay = y - y0f;
        float wxs[2] = {1.0f - ax, ax};
        float wys[2] = {1.0f - ay, ay};
        bool cxs[2] = {cx0, cx1};
        bool cys[2] = {cy0, cy1};
        #pragma unroll
        for (int ky = 0; ky < 2; ++ky) {
            if (!cys[ky]) continue;
            #pragma unroll
            for (int kx = 0; kx < 2; ++kx) {
                if (!cxs[kx]) continue;
                float wt = wxs[kx] * wys[ky];
                int la = (iy0 + ky) * TW_ + (ix0 + kx);
                atomicAdd(&acc[la], v0v[k] * wt);
                atomicAdd(&acc[la + PLANE_STRIDE_], v1v[k] * wt);
                atomicAdd(&acc[la + 2 * PLANE_STRIDE_], v2v[k] * wt);
            }
        }
    }
    __syncthreads();

    // ---- phase 3: exclusive coalesced nontemporal float4 write-out ----
    const size_t outb = (size_t)b * C_ * Ho_ * Wo_;
    const size_t chs  = (size_t)Ho_ * Wo_;
    const int F4_PER_PLANE = TH_ * TW_ / 4;        // 640
    const int F4_PER_ROW   = TW_ / 4;              // 16
    for (int j = threadIdx.x; j < C_ * F4_PER_PLANE; j += 256) {
        int ch  = j / F4_PER_PLANE;
        int rem = j - ch * F4_PER_PLANE;
        int yy  = rem / F4_PER_ROW;
        int xx4 = rem - yy * F4_PER_ROW;
        f32x4 v = *reinterpret_cast<const f32x4*>(&acc[ch * PLANE_STRIDE_ + yy * TW_ + xx4 * 4]);
        __builtin_nontemporal_store(v,
            reinterpret_cast<f32x4*>(
                &out[outb + (size_t)ch * chs + (size_t)(py0 + yy) * Wo_ + px0 + xx4 * 4]));
    }
}

// Pixels with |flow| > MARGIN_: exact global-atomic splat (AFTER tile writes).
// Vectorized: 4 px/thread via f32x4 flow loads; fast path = all inliers.
__global__ __launch_bounds__(256) void outlier_kernel(const float* __restrict__ img,
                                                      const float* __restrict__ flow,
                                                      float* __restrict__ out) {
    int q = blockIdx.x * 256 + threadIdx.x;   // grid exactly NPIX_/4/256 = 450
    int idx = q * 4;
    int b = idx / HW_;                         // HW_ % 4 == 0 -> same b for all 4
    int hw = idx - b * HW_;
    f32x4 fx4 = *reinterpret_cast<const f32x4*>(&flow[(size_t)(b * 2 + 0) * HW_ + hw]);
    f32x4 fy4 = *reinterpret_cast<const f32x4*>(&flow[(size_t)(b * 2 + 1) * HW_ + hw]);

    bool ol[4];
    bool any = false;
    #pragma unroll
    for (int j = 0; j < 4; ++j) {
        ol[j] = !(fabsf(fx4[j]) <= MARGIN_ && fabsf(fy4[j]) <= MARGIN_);
        any |= ol[j];
    }
    if (!any) return;

    const float* imgb = img + (size_t)b * C_ * HW_;
    const size_t out_b = (size_t)b * C_ * Ho_ * Wo_;
    const size_t chs = (size_t)Ho_ * Wo_;
    #pragma unroll
    for (int j = 0; j < 4; ++j) {
        if (!ol[j]) continue;
        int hwj = hw + j;
        int h = hwj / W_;
        int w = hwj - h * W_;
        float x = ((float)w + fx4[j]) * (float)SCALE_;
        float y = ((float)h + fy4[j]) * (float)SCALE_;
        float x0f = floorf(x), y0f = floorf(y);
        float ax = x - x0f, ay = y - y0f;
        int ix0 = (int)x0f, iy0 = (int)y0f;
        float v0 = imgb[hwj];
        float v1 = imgb[HW_ + hwj];
        float v2 = imgb[2 * HW_ + hwj];
        float wxs[2] = {1.0f - ax, ax};
        float wys[2] = {1.0f - ay, ay};
        #pragma unroll
        for (int ky = 0; ky < 2; ++ky) {
            int yi = iy0 + ky;
            if ((unsigned)yi >= (unsigned)Ho_) continue;
            #pragma unroll
            for (int kx = 0; kx < 2; ++kx) {
                int xi = ix0 + kx;
                if ((unsigned)xi >= (unsigned)Wo_) continue;
                float wt = wxs[kx] * wys[ky];
                size_t base = out_b + (size_t)yi * Wo_ + (size_t)xi;
                atomicAdd(&out[base + 0 * chs], v0 * wt);
                atomicAdd(&out[base + 1 * chs], v1 * wt);
                atomicAdd(&out[base + 2 * chs], v2 * wt);
            }
        }
    }
}

// ---------------- fallback: naive global-atomic splat (scale != 4) ----------------
__global__ __launch_bounds__(256) void splat_naive(const float* __restrict__ img,
                                                   const float* __restrict__ flow,
                                                   const int* __restrict__ scale_p,
                                                   float* __restrict__ out) {
    int idx = blockIdx.x * blockDim.x + threadIdx.x;
    if (idx >= NPIX_) return;
    const int s = *scale_p;
    const int Ho = H_ * s, Wo = W_ * s;
    int w = idx % W_;
    int t = idx / W_;
    int h = t % H_;
    int b = t / H_;
    const int hw = h * W_ + w;
    float fx = flow[((b * 2 + 0) * H_) * W_ + hw];
    float fy = flow[((b * 2 + 1) * H_) * W_ + hw];
    float x = ((float)w + fx) * (float)s;
    float y = ((float)h + fy) * (float)s;
    float x0f = floorf(x), y0f = floorf(y);
    float ax = x - x0f, ay = y - y0f;
    int ix0 = (int)x0f, iy0 = (int)y0f;
    const size_t img_b = (size_t)b * C_ * HW_;
    float v0 = img[img_b + 0 * (size_t)HW_ + hw];
    float v1 = img[img_b + 1 * (size_t)HW_ + hw];
    float v2 = img[img_b + 2 * (size_t)HW_ + hw];
    const size_t out_b = (size_t)b * C_ * Ho * Wo;
    const size_t out_chs = (size_t)Ho * Wo;
    float wxs[2] = {1.0f - ax, ax};
    float wys[2] = {1.0f - ay, ay};
    #pragma unroll
    for (int ky = 0; ky < 2; ++ky) {
        int yi = iy0 + ky;
        if (yi < 0 || yi > Ho - 1) continue;
        #pragma unroll
        for (int kx = 0; kx < 2; ++kx) {
            int xi = ix0 + kx;
            if (xi < 0 || xi > Wo - 1) continue;
            float wt = wxs[kx] * wys[ky];
            size_t base = out_b + (size_t)yi * Wo + (size_t)xi;
            atomicAdd(&out[base + 0 * out_chs], v0 * wt);
            atomicAdd(&out[base + 1 * out_chs], v1 * wt);
            atomicAdd(&out[base + 2 * out_chs], v2 * wt);
        }
    }
}

extern "C" void kernel_launch(void* const* d_in, const int* in_sizes, int n_in,
                              void* d_out, int out_size, void* d_ws, size_t ws_size,
                              hipStream_t stream) {
    const float* img   = (const float*)d_in[0];
    const float* flow  = (const float*)d_in[1];
    const int*   scale = (const int*)d_in[2];
    float* out = (float*)d_out;

    const bool scale4 = (out_size == B_ * C_ * Ho_ * Wo_);

    if (scale4) {
        warp_tile_kernel<<<NTILES_, 256, 0, stream>>>(img, flow, out);
        outlier_kernel<<<NPIX_ / 4 / 256, 256, 0, stream>>>(img, flow, out);
    } else {
        (void)hipMemsetAsync(out, 0, (size_t)out_size * sizeof(float), stream);
        splat_naive<<<(NPIX_ + 255) / 256, 256, 0, stream>>>(img, flow, scale, out);
    }
}

// Round 13
// 43.894 us; speedup vs baseline: 1.1664x; 1.0224x over previous
//
#include <hip/hip_runtime.h>
#include <hip/hip_bf16.h>

// Forward warp (bilinear splatting), direct per-tile gather-from-window.
//   img  [B=8, C=3, H=180, W=320] f32
//   flow [B=8, 2,  H=180, W=320] f32
//   scale=4 -> out [B, C, 720, 1280] f32
//
// R13 = R7 champion skeleton with VECTORIZED phase-1 loads:
//   window = 28 rows x 10 aligned 4-px strips (cols wb-12..wb+27, every strip
//   16B-aligned and fully in-row or fully out since W%4==0). Each thread owns
//   1-2 strips -> 5 (or 10) f32x4 loads instead of 20 scalar loads. Extra
//   columns beyond the margin-8 window are harmless: they cannot pass the
//   tile hit test, and per-corner hit regions are disjoint across tiles.
// Phase order (load-bearing, R7-verified): LDS zero -> sync -> batched loads
// -> predicate+LDS atomics -> sync -> nontemporal exclusive write-out.
// Pixels with |flow| > 8 go through the EXACT-complement outlier kernel
// (global atomics AFTER tile stores; ordering requires separate dispatch).

typedef float f32x4 __attribute__((ext_vector_type(4)));

#define B_ 8
#define C_ 3
#define H_ 180
#define W_ 320
#define HW_ (H_ * W_)
#define SCALE_ 4
#define Ho_ (H_ * SCALE_)            // 720
#define Wo_ (W_ * SCALE_)            // 1280
#define TH_ 40
#define TW_ 64
#define NTY_ (Ho_ / TH_)             // 18
#define NTX_ (Wo_ / TW_)             // 20
#define NTILES_ (B_ * NTY_ * NTX_)   // 2880 (divisible by 8 -> bijective XCD swizzle)
#define NPIX_ (B_ * H_ * W_)         // 460800

#define MARGIN_ 8.0f
#define WIN_H_ 28                    // rows hb-9 .. hb+18
#define NSTRIP_W_ 10                 // strips of 4 cols: wb-12 .. wb+27
#define NSTRIPS_ (WIN_H_ * NSTRIP_W_)  // 280
#define PLANE_STRIDE_ 2564           // 2560+4: channel atomics -> distinct banks, 16B-aligned
#define LDS_FLOATS_ (C_ * PLANE_STRIDE_)   // 7692 floats = 30768 B -> 5 blocks/CU

__global__ __launch_bounds__(256) void warp_tile_kernel(const float* __restrict__ img,
                                                        const float* __restrict__ flow,
                                                        float* __restrict__ out) {
    __shared__ __align__(16) float acc[LDS_FLOATS_];
    const int tid = threadIdx.x;

    // XCD-chunked swizzle (2880 % 8 == 0 -> bijective).
    int tile = (int)(blockIdx.x & 7) * (NTILES_ / 8) + (int)(blockIdx.x >> 3);
    const int tx = tile % NTX_;
    const int tt = tile / NTX_;
    const int ty = tt % NTY_;
    const int b  = tt / NTY_;
    const int px0 = tx * TW_;
    const int py0 = ty * TH_;

    for (int j = tid; j < LDS_FLOATS_ / 4; j += 256)
        *reinterpret_cast<f32x4*>(&acc[j * 4]) = (f32x4)(0.f);
    __syncthreads();

    const float* __restrict__ fxp  = flow + (size_t)(b * 2 + 0) * HW_;
    const float* __restrict__ fyp  = flow + (size_t)(b * 2 + 1) * HW_;
    const float* __restrict__ imgb = img + (size_t)b * C_ * HW_;

    const int hb = py0 >> 2;
    const int wb = px0 >> 2;

    // ---- phase 1: batched vector loads (1-2 strips/thread, 5 f32x4 each) ----
    f32x4 fx4[2], fy4[2], v04[2], v14[2], v24[2];
    bool av[2];
    int h_[2], w0_[2];
    #pragma unroll
    for (int k = 0; k < 2; ++k) {
        int si = tid + k * 256;
        int r = si / NSTRIP_W_;
        int s = si - r * NSTRIP_W_;
        int h  = hb - 9 + r;
        int w0 = wb - 12 + 4 * s;
        // strip fully in-row or fully out (w0 % 4 == 0, W % 4 == 0)
        bool act = (si < NSTRIPS_) &&
                   ((unsigned)h < (unsigned)H_) && ((unsigned)w0 < (unsigned)W_);
        av[k] = act; h_[k] = h; w0_[k] = w0;
        int hw = act ? (h * W_ + w0) : 0;
        fx4[k] = *reinterpret_cast<const f32x4*>(&fxp[hw]);
        fy4[k] = *reinterpret_cast<const f32x4*>(&fyp[hw]);
        v04[k] = *reinterpret_cast<const f32x4*>(&imgb[hw]);
        v14[k] = *reinterpret_cast<const f32x4*>(&imgb[HW_ + hw]);
        v24[k] = *reinterpret_cast<const f32x4*>(&imgb[2 * HW_ + hw]);
    }

    // ---- phase 2: predicate + hit-test + LDS accumulate ----
    #pragma unroll
    for (int k = 0; k < 2; ++k) {
        if (!av[k]) continue;
        #pragma unroll
        for (int j = 0; j < 4; ++j) {
            float fx = fx4[k][j], fy = fy4[k][j];
            // Must be the EXACT complement of outlier_kernel's predicate.
            if (!(fabsf(fx) <= MARGIN_ && fabsf(fy) <= MARGIN_)) continue;

            float x = ((float)(w0_[k] + j) + fx) * (float)SCALE_;
            float y = ((float)h_[k] + fy) * (float)SCALE_;
            float x0f = floorf(x), y0f = floorf(y);
            int ix0 = (int)x0f - px0;   // tile-local
            int iy0 = (int)y0f - py0;
            bool cx0 = (unsigned)ix0 < (unsigned)TW_;
            bool cx1 = (unsigned)(ix0 + 1) < (unsigned)TW_;
            bool cy0 = (unsigned)iy0 < (unsigned)TH_;
            bool cy1 = (unsigned)(iy0 + 1) < (unsigned)TH_;
            if (!((cx0 | cx1) & (cy0 | cy1))) continue;

            float ax = x - x0f, ay = y - y0f;
            float wxs[2] = {1.0f - ax, ax};
            float wys[2] = {1.0f - ay, ay};
            bool cxs[2] = {cx0, cx1};
            bool cys[2] = {cy0, cy1};
            float v0 = v04[k][j], v1 = v14[k][j], v2 = v24[k][j];
            #pragma unroll
            for (int ky = 0; ky < 2; ++ky) {
                if (!cys[ky]) continue;
                #pragma unroll
                for (int kx = 0; kx < 2; ++kx) {
                    if (!cxs[kx]) continue;
                    float wt = wxs[kx] * wys[ky];
                    int la = (iy0 + ky) * TW_ + (ix0 + kx);
                    atomicAdd(&acc[la], v0 * wt);
                    atomicAdd(&acc[la + PLANE_STRIDE_], v1 * wt);
                    atomicAdd(&acc[la + 2 * PLANE_STRIDE_], v2 * wt);
                }
            }
        }
    }
    __syncthreads();

    // ---- phase 3: exclusive coalesced nontemporal float4 write-out ----
    const size_t outb = (size_t)b * C_ * Ho_ * Wo_;
    const size_t chs  = (size_t)Ho_ * Wo_;
    const int F4_PER_PLANE = TH_ * TW_ / 4;        // 640
    const int F4_PER_ROW   = TW_ / 4;              // 16
    for (int j = tid; j < C_ * F4_PER_PLANE; j += 256) {
        int ch  = j / F4_PER_PLANE;
        int rem = j - ch * F4_PER_PLANE;
        int yy  = rem / F4_PER_ROW;
        int xx4 = rem - yy * F4_PER_ROW;
        f32x4 v = *reinterpret_cast<const f32x4*>(&acc[ch * PLANE_STRIDE_ + yy * TW_ + xx4 * 4]);
        __builtin_nontemporal_store(v,
            reinterpret_cast<f32x4*>(
                &out[outb + (size_t)ch * chs + (size_t)(py0 + yy) * Wo_ + px0 + xx4 * 4]));
    }
}

// Pixels with |flow| > MARGIN_: exact global-atomic splat (AFTER tile writes).
// Vectorized: 4 px/thread via f32x4 flow loads; fast path = all inliers.
__global__ __launch_bounds__(256) void outlier_kernel(const float* __restrict__ img,
                                                      const float* __restrict__ flow,
                                                      float* __restrict__ out) {
    int q = blockIdx.x * 256 + threadIdx.x;   // grid exactly NPIX_/4/256 = 450
    int idx = q * 4;
    int b = idx / HW_;                         // HW_ % 4 == 0 -> same b for all 4
    int hw = idx - b * HW_;
    f32x4 fx4 = *reinterpret_cast<const f32x4*>(&flow[(size_t)(b * 2 + 0) * HW_ + hw]);
    f32x4 fy4 = *reinterpret_cast<const f32x4*>(&flow[(size_t)(b * 2 + 1) * HW_ + hw]);

    bool ol[4];
    bool any = false;
    #pragma unroll
    for (int j = 0; j < 4; ++j) {
        ol[j] = !(fabsf(fx4[j]) <= MARGIN_ && fabsf(fy4[j]) <= MARGIN_);
        any |= ol[j];
    }
    if (!any) return;

    const float* imgb = img + (size_t)b * C_ * HW_;
    const size_t out_b = (size_t)b * C_ * Ho_ * Wo_;
    const size_t chs = (size_t)Ho_ * Wo_;
    #pragma unroll
    for (int j = 0; j < 4; ++j) {
        if (!ol[j]) continue;
        int hwj = hw + j;
        int h = hwj / W_;
        int w = hwj - h * W_;
        float x = ((float)w + fx4[j]) * (float)SCALE_;
        float y = ((float)h + fy4[j]) * (float)SCALE_;
        float x0f = floorf(x), y0f = floorf(y);
        float ax = x - x0f, ay = y - y0f;
        int ix0 = (int)x0f, iy0 = (int)y0f;
        float v0 = imgb[hwj];
        float v1 = imgb[HW_ + hwj];
        float v2 = imgb[2 * HW_ + hwj];
        float wxs[2] = {1.0f - ax, ax};
        float wys[2] = {1.0f - ay, ay};
        #pragma unroll
        for (int ky = 0; ky < 2; ++ky) {
            int yi = iy0 + ky;
            if ((unsigned)yi >= (unsigned)Ho_) continue;
            #pragma unroll
            for (int kx = 0; kx < 2; ++kx) {
                int xi = ix0 + kx;
                if ((unsigned)xi >= (unsigned)Wo_) continue;
                float wt = wxs[kx] * wys[ky];
                size_t base = out_b + (size_t)yi * Wo_ + (size_t)xi;
                atomicAdd(&out[base + 0 * chs], v0 * wt);
                atomicAdd(&out[base + 1 * chs], v1 * wt);
                atomicAdd(&out[base + 2 * chs], v2 * wt);
            }
        }
    }
}

// ---------------- fallback: naive global-atomic splat (scale != 4) ----------------
__global__ __launch_bounds__(256) void splat_naive(const float* __restrict__ img,
                                                   const float* __restrict__ flow,
                                                   const int* __restrict__ scale_p,
                                                   float* __restrict__ out) {
    int idx = blockIdx.x * blockDim.x + threadIdx.x;
    if (idx >= NPIX_) return;
    const int s = *scale_p;
    const int Ho = H_ * s, Wo = W_ * s;
    int w = idx % W_;
    int t = idx / W_;
    int h = t % H_;
    int b = t / H_;
    const int hw = h * W_ + w;
    float fx = flow[((b * 2 + 0) * H_) * W_ + hw];
    float fy = flow[((b * 2 + 1) * H_) * W_ + hw];
    float x = ((float)w + fx) * (float)s;
    float y = ((float)h + fy) * (float)s;
    float x0f = floorf(x), y0f = floorf(y);
    float ax = x - x0f, ay = y - y0f;
    int ix0 = (int)x0f, iy0 = (int)y0f;
    const size_t img_b = (size_t)b * C_ * HW_;
    float v0 = img[img_b + 0 * (size_t)HW_ + hw];
    float v1 = img[img_b + 1 * (size_t)HW_ + hw];
    float v2 = img[img_b + 2 * (size_t)HW_ + hw];
    const size_t out_b = (size_t)b * C_ * Ho * Wo;
    const size_t out_chs = (size_t)Ho * Wo;
    float wxs[2] = {1.0f - ax, ax};
    float wys[2] = {1.0f - ay, ay};
    #pragma unroll
    for (int ky = 0; ky < 2; ++ky) {
        int yi = iy0 + ky;
        if (yi < 0 || yi > Ho - 1) continue;
        #pragma unroll
        for (int kx = 0; kx < 2; ++kx) {
            int xi = ix0 + kx;
            if (xi < 0 || xi > Wo - 1) continue;
            float wt = wxs[kx] * wys[ky];
            size_t base = out_b + (size_t)yi * Wo + (size_t)xi;
            atomicAdd(&out[base + 0 * out_chs], v0 * wt);
            atomicAdd(&out[base + 1 * out_chs], v1 * wt);
            atomicAdd(&out[base + 2 * out_chs], v2 * wt);
        }
    }
}

extern "C" void kernel_launch(void* const* d_in, const int* in_sizes, int n_in,
                              void* d_out, int out_size, void* d_ws, size_t ws_size,
                              hipStream_t stream) {
    const float* img   = (const float*)d_in[0];
    const float* flow  = (const float*)d_in[1];
    const int*   scale = (const int*)d_in[2];
    float* out = (float*)d_out;

    const bool scale4 = (out_size == B_ * C_ * Ho_ * Wo_);

    if (scale4) {
        warp_tile_kernel<<<NTILES_, 256, 0, stream>>>(img, flow, out);
        outlier_kernel<<<NPIX_ / 4 / 256, 256, 0, stream>>>(img, flow, out);
    } else {
        (void)hipMemsetAsync(out, 0, (size_t)out_size * sizeof(float), stream);
        splat_naive<<<(NPIX_ + 255) / 256, 256, 0, stream>>>(img, flow, scale, out);
    }
}

// Round 14
// 42.858 us; speedup vs baseline: 1.1946x; 1.0242x over previous
//
#include <hip/hip_runtime.h>
#include <hip/hip_bf16.h>

// Forward warp (bilinear splatting), direct per-tile gather-from-window.
//   img  [B=8, C=3, H=180, W=320] f32
//   flow [B=8, 2,  H=180, W=320] f32
//   scale=4 -> out [B, C, 720, 1280] f32
//
// R14 = champion skeleton at 40x32 tiles for MAX occupancy:
//   LDS 15.4 KB -> 8 blocks/CU (thread-slot capped) = 32 waves/CU (HW max),
//   vs 20 waves at 40x64. 5760 blocks; window = 28 rows x 8 aligned strips
//   (cols wb-12..wb+19 superset of needed [wb-9,wb+16]; extras provably fail
//   the hit test at |flow|<=8) -> 224 strips, ONE strip per thread, 5 f32x4
//   loads, no per-thread loop. Phase order (load-bearing, R7-verified):
//   zero -> sync -> batched loads -> predicate+LDS atomics -> sync ->
//   nontemporal exclusive write-out. |flow| > 8 pixels go through the
//   EXACT-complement vectorized outlier kernel (separate dispatch AFTER
//   tile stores; ordering requires it).

typedef float f32x4 __attribute__((ext_vector_type(4)));

#define B_ 8
#define C_ 3
#define H_ 180
#define W_ 320
#define HW_ (H_ * W_)
#define SCALE_ 4
#define Ho_ (H_ * SCALE_)            // 720
#define Wo_ (W_ * SCALE_)            // 1280
#define TH_ 40
#define TW_ 32
#define NTY_ (Ho_ / TH_)             // 18
#define NTX_ (Wo_ / TW_)             // 40
#define NTILES_ (B_ * NTY_ * NTX_)   // 5760 (divisible by 8 -> bijective XCD swizzle)
#define NPIX_ (B_ * H_ * W_)         // 460800

#define MARGIN_ 8.0f
#define WIN_H_ 28                    // rows hb-9 .. hb+18
#define NSTRIP_W_ 8                  // strips of 4 cols: wb-12 .. wb+19
#define NSTRIPS_ (WIN_H_ * NSTRIP_W_)  // 224 (<= 256: one strip per thread)
#define PLANE_STRIDE_ 1284           // 1280+4: channel atomics -> distinct banks, 16B-aligned
#define LDS_FLOATS_ (C_ * PLANE_STRIDE_)   // 3852 floats = 15408 B -> 8 blocks/CU (thread cap)

__global__ __launch_bounds__(256) void warp_tile_kernel(const float* __restrict__ img,
                                                        const float* __restrict__ flow,
                                                        float* __restrict__ out) {
    __shared__ __align__(16) float acc[LDS_FLOATS_];
    const int tid = threadIdx.x;

    // XCD-chunked swizzle (5760 % 8 == 0 -> bijective).
    int tile = (int)(blockIdx.x & 7) * (NTILES_ / 8) + (int)(blockIdx.x >> 3);
    const int tx = tile % NTX_;
    const int tt = tile / NTX_;
    const int ty = tt % NTY_;
    const int b  = tt / NTY_;
    const int px0 = tx * TW_;
    const int py0 = ty * TH_;

    for (int j = tid; j < LDS_FLOATS_ / 4; j += 256)
        *reinterpret_cast<f32x4*>(&acc[j * 4]) = (f32x4)(0.f);
    __syncthreads();

    const float* __restrict__ fxp  = flow + (size_t)(b * 2 + 0) * HW_;
    const float* __restrict__ fyp  = flow + (size_t)(b * 2 + 1) * HW_;
    const float* __restrict__ imgb = img + (size_t)b * C_ * HW_;

    const int hb = py0 >> 2;   // 10*ty
    const int wb = px0 >> 2;   // 8*tx (multiple of 8 -> strips 4-aligned)

    // ---- phase 1: one aligned 4-px strip per thread, 5 f32x4 batched loads ----
    const int r  = tid / NSTRIP_W_;
    const int s  = tid - r * NSTRIP_W_;
    const int h  = hb - 9 + r;
    const int w0 = wb - 12 + 4 * s;
    // strip fully in-row or fully out (w0 % 4 == 0, W % 4 == 0)
    const bool act = (tid < NSTRIPS_) &&
                     ((unsigned)h < (unsigned)H_) && ((unsigned)w0 < (unsigned)W_);
    const int hw = act ? (h * W_ + w0) : 0;
    f32x4 fx4 = *reinterpret_cast<const f32x4*>(&fxp[hw]);
    f32x4 fy4 = *reinterpret_cast<const f32x4*>(&fyp[hw]);
    f32x4 v04 = *reinterpret_cast<const f32x4*>(&imgb[hw]);
    f32x4 v14 = *reinterpret_cast<const f32x4*>(&imgb[HW_ + hw]);
    f32x4 v24 = *reinterpret_cast<const f32x4*>(&imgb[2 * HW_ + hw]);

    // ---- phase 2: predicate + hit-test + LDS accumulate ----
    if (act) {
        #pragma unroll
        for (int j = 0; j < 4; ++j) {
            float fx = fx4[j], fy = fy4[j];
            // Must be the EXACT complement of outlier_kernel's predicate.
            if (!(fabsf(fx) <= MARGIN_ && fabsf(fy) <= MARGIN_)) continue;

            float x = ((float)(w0 + j) + fx) * (float)SCALE_;
            float y = ((float)h + fy) * (float)SCALE_;
            float x0f = floorf(x), y0f = floorf(y);
            int ix0 = (int)x0f - px0;   // tile-local
            int iy0 = (int)y0f - py0;
            bool cx0 = (unsigned)ix0 < (unsigned)TW_;
            bool cx1 = (unsigned)(ix0 + 1) < (unsigned)TW_;
            bool cy0 = (unsigned)iy0 < (unsigned)TH_;
            bool cy1 = (unsigned)(iy0 + 1) < (unsigned)TH_;
            if (!((cx0 | cx1) & (cy0 | cy1))) continue;

            float ax = x - x0f, ay = y - y0f;
            float wxs[2] = {1.0f - ax, ax};
            float wys[2] = {1.0f - ay, ay};
            bool cxs[2] = {cx0, cx1};
            bool cys[2] = {cy0, cy1};
            float v0 = v04[j], v1 = v14[j], v2 = v24[j];
            #pragma unroll
            for (int ky = 0; ky < 2; ++ky) {
                if (!cys[ky]) continue;
                #pragma unroll
                for (int kx = 0; kx < 2; ++kx) {
                    if (!cxs[kx]) continue;
                    float wt = wxs[kx] * wys[ky];
                    int la = (iy0 + ky) * TW_ + (ix0 + kx);
                    atomicAdd(&acc[la], v0 * wt);
                    atomicAdd(&acc[la + PLANE_STRIDE_], v1 * wt);
                    atomicAdd(&acc[la + 2 * PLANE_STRIDE_], v2 * wt);
                }
            }
        }
    }
    __syncthreads();

    // ---- phase 3: exclusive coalesced nontemporal float4 write-out ----
    const size_t outb = (size_t)b * C_ * Ho_ * Wo_;
    const size_t chs  = (size_t)Ho_ * Wo_;
    const int F4_PER_PLANE = TH_ * TW_ / 4;        // 320
    const int F4_PER_ROW   = TW_ / 4;              // 8
    #pragma unroll
    for (int j = tid; j < C_ * F4_PER_PLANE; j += 256) {   // 960 total, <=4 iters
        int ch  = j / F4_PER_PLANE;
        int rem = j - ch * F4_PER_PLANE;
        int yy  = rem / F4_PER_ROW;
        int xx4 = rem - yy * F4_PER_ROW;
        f32x4 v = *reinterpret_cast<const f32x4*>(&acc[ch * PLANE_STRIDE_ + yy * TW_ + xx4 * 4]);
        __builtin_nontemporal_store(v,
            reinterpret_cast<f32x4*>(
                &out[outb + (size_t)ch * chs + (size_t)(py0 + yy) * Wo_ + px0 + xx4 * 4]));
    }
}

// Pixels with |flow| > MARGIN_: exact global-atomic splat (AFTER tile writes).
// Vectorized: 4 px/thread via f32x4 flow loads; fast path = all inliers.
__global__ __launch_bounds__(256) void outlier_kernel(const float* __restrict__ img,
                                                      const float* __restrict__ flow,
                                                      float* __restrict__ out) {
    int q = blockIdx.x * 256 + threadIdx.x;   // grid exactly NPIX_/4/256 = 450
    int idx = q * 4;
    int b = idx / HW_;                         // HW_ % 4 == 0 -> same b for all 4
    int hw = idx - b * HW_;
    f32x4 fx4 = *reinterpret_cast<const f32x4*>(&flow[(size_t)(b * 2 + 0) * HW_ + hw]);
    f32x4 fy4 = *reinterpret_cast<const f32x4*>(&flow[(size_t)(b * 2 + 1) * HW_ + hw]);

    bool ol[4];
    bool any = false;
    #pragma unroll
    for (int j = 0; j < 4; ++j) {
        ol[j] = !(fabsf(fx4[j]) <= MARGIN_ && fabsf(fy4[j]) <= MARGIN_);
        any |= ol[j];
    }
    if (!any) return;

    const float* imgb = img + (size_t)b * C_ * HW_;
    const size_t out_b = (size_t)b * C_ * Ho_ * Wo_;
    const size_t chs = (size_t)Ho_ * Wo_;
    #pragma unroll
    for (int j = 0; j < 4; ++j) {
        if (!ol[j]) continue;
        int hwj = hw + j;
        int h = hwj / W_;
        int w = hwj - h * W_;
        float x = ((float)w + fx4[j]) * (float)SCALE_;
        float y = ((float)h + fy4[j]) * (float)SCALE_;
        float x0f = floorf(x), y0f = floorf(y);
        float ax = x - x0f, ay = y - y0f;
        int ix0 = (int)x0f, iy0 = (int)y0f;
        float v0 = imgb[hwj];
        float v1 = imgb[HW_ + hwj];
        float v2 = imgb[2 * HW_ + hwj];
        float wxs[2] = {1.0f - ax, ax};
        float wys[2] = {1.0f - ay, ay};
        #pragma unroll
        for (int ky = 0; ky < 2; ++ky) {
            int yi = iy0 + ky;
            if ((unsigned)yi >= (unsigned)Ho_) continue;
            #pragma unroll
            for (int kx = 0; kx < 2; ++kx) {
                int xi = ix0 + kx;
                if ((unsigned)xi >= (unsigned)Wo_) continue;
                float wt = wxs[kx] * wys[ky];
                size_t base = out_b + (size_t)yi * Wo_ + (size_t)xi;
                atomicAdd(&out[base + 0 * chs], v0 * wt);
                atomicAdd(&out[base + 1 * chs], v1 * wt);
                atomicAdd(&out[base + 2 * chs], v2 * wt);
            }
        }
    }
}

// ---------------- fallback: naive global-atomic splat (scale != 4) ----------------
__global__ __launch_bounds__(256) void splat_naive(const float* __restrict__ img,
                                                   const float* __restrict__ flow,
                                                   const int* __restrict__ scale_p,
                                                   float* __restrict__ out) {
    int idx = blockIdx.x * blockDim.x + threadIdx.x;
    if (idx >= NPIX_) return;
    const int s = *scale_p;
    const int Ho = H_ * s, Wo = W_ * s;
    int w = idx % W_;
    int t = idx / W_;
    int h = t % H_;
    int b = t / H_;
    const int hw = h * W_ + w;
    float fx = flow[((b * 2 + 0) * H_) * W_ + hw];
    float fy = flow[((b * 2 + 1) * H_) * W_ + hw];
    float x = ((float)w + fx) * (float)s;
    float y = ((float)h + fy) * (float)s;
    float x0f = floorf(x), y0f = floorf(y);
    float ax = x - x0f, ay = y - y0f;
    int ix0 = (int)x0f, iy0 = (int)y0f;
    const size_t img_b = (size_t)b * C_ * HW_;
    float v0 = img[img_b + 0 * (size_t)HW_ + hw];
    float v1 = img[img_b + 1 * (size_t)HW_ + hw];
    float v2 = img[img_b + 2 * (size_t)HW_ + hw];
    const size_t out_b = (size_t)b * C_ * Ho * Wo;
    const size_t out_chs = (size_t)Ho * Wo;
    float wxs[2] = {1.0f - ax, ax};
    float wys[2] = {1.0f - ay, ay};
    #pragma unroll
    for (int ky = 0; ky < 2; ++ky) {
        int yi = iy0 + ky;
        if (yi < 0 || yi > Ho - 1) continue;
        #pragma unroll
        for (int kx = 0; kx < 2; ++kx) {
            int xi = ix0 + kx;
            if (xi < 0 || xi > Wo - 1) continue;
            float wt = wxs[kx] * wys[ky];
            size_t base = out_b + (size_t)yi * Wo + (size_t)xi;
            atomicAdd(&out[base + 0 * out_chs], v0 * wt);
            atomicAdd(&out[base + 1 * out_chs], v1 * wt);
            atomicAdd(&out[base + 2 * out_chs], v2 * wt);
        }
    }
}

extern "C" void kernel_launch(void* const* d_in, const int* in_sizes, int n_in,
                              void* d_out, int out_size, void* d_ws, size_t ws_size,
                              hipStream_t stream) {
    const float* img   = (const float*)d_in[0];
    const float* flow  = (const float*)d_in[1];
    const int*   scale = (const int*)d_in[2];
    float* out = (float*)d_out;

    const bool scale4 = (out_size == B_ * C_ * Ho_ * Wo_);

    if (scale4) {
        warp_tile_kernel<<<NTILES_, 256, 0, stream>>>(img, flow, out);
        outlier_kernel<<<NPIX_ / 4 / 256, 256, 0, stream>>>(img, flow, out);
    } else {
        (void)hipMemsetAsync(out, 0, (size_t)out_size * sizeof(float), stream);
        splat_naive<<<(NPIX_ + 255) / 256, 256, 0, stream>>>(img, flow, scale, out);
    }
}